// Round 1
// baseline (18190.007 us; speedup 1.0000x reference)
//
#include <hip/hip_runtime.h>
#include <hip/hip_bf16.h>

#define D 512
#define H 16
#define HD 32
#define LAYERS 24
#define FF 2048
#define MAX_DECODE 1500
#define TOTAL 1024
#define CACHE_ROWS (TOTAL + MAX_DECODE)   // 2524
#define VOCAB_AUD 1025

// ---------------------------------------------------------------------------
// Sinusoidal PE (float32, matches numpy: div = exp(2j * (-log(10000)/512)))
// ---------------------------------------------------------------------------
__device__ __forceinline__ float pe_val(int pos, int c) {
    int j = c & ~1;  // 2*floor(c/2)
    float div = expf((float)j * -0.017988946039015984f);  // -log(10000)/512
    float ang = (float)pos * div;
    return (c & 1) ? cosf(ang) : sinf(ang);
}

// ---------------------------------------------------------------------------
// Build packed input h (TOTAL x D):
//  t < ref_len              : text_emb[ref_seq[t]]  + refproj[t]  + at*pe[t]
//  ref_len <= t < x_len     : text_emb[text_seq[i]] + textproj[i] + at*pe[t]
//  x_len <= t < tot         : audio_emb[prompts[i]]*(i<p_len) + aa*pe[i]
//  t >= tot                 : 0
// (refproj/textproj already include bert_proj_b via GEMM bias)
// ---------------------------------------------------------------------------
__global__ void build_h(const int* __restrict__ prompts, const int* __restrict__ pl,
                        const int* __restrict__ ref_seq, const int* __restrict__ rl,
                        const int* __restrict__ text_seq, const int* __restrict__ tl,
                        const float* __restrict__ text_emb, const float* __restrict__ audio_emb,
                        const float* __restrict__ refproj, const float* __restrict__ textproj,
                        const float* __restrict__ alpha_text, const float* __restrict__ alpha_audio,
                        float* __restrict__ h) {
    const int t = blockIdx.x;
    const int ref_len = rl[0], text_len = tl[0], p_len = pl[0];
    const int x_len = ref_len + text_len;
    const int tot = x_len + p_len;
    const float at = alpha_text[0], aa = alpha_audio[0];
    for (int c = threadIdx.x; c < D; c += 256) {
        float val = 0.f;
        if (t < x_len) {
            float pe = at * pe_val(t, c);
            if (t < ref_len)
                val = text_emb[ref_seq[t] * D + c] + refproj[t * D + c] + pe;
            else
                val = text_emb[text_seq[t - ref_len] * D + c] + textproj[(t - ref_len) * D + c] + pe;
        } else if (t < tot) {
            int i = t - x_len;
            float pe = aa * pe_val(i, c);
            float a = (i < p_len) ? audio_emb[prompts[i] * D + c] : 0.f;
            val = a + pe;
        }
        h[t * D + c] = val;
    }
}

// ---------------------------------------------------------------------------
// Generic tiled GEMM: C[M,N] = A @ B + bias, optional A^T (A stored K x M),
// optional ReLU. BM=BN=64, BK=16, 256 threads, 4x4 per thread.
// Requires M%64==0, N%64==0, K%16==0.
// ---------------------------------------------------------------------------
template <bool TA, bool RELU>
__global__ __launch_bounds__(256) void gemm64(const float* __restrict__ A,
                                              const float* __restrict__ B,
                                              const float* __restrict__ bias,
                                              float* __restrict__ C,
                                              int M, int K, int N) {
    __shared__ float As[16][65];
    __shared__ float Bs[16][64];
    const int tid = threadIdx.x;
    const int tx = tid & 15, ty = tid >> 4;
    const int m0 = blockIdx.y * 64, n0 = blockIdx.x * 64;
    float acc[4][4] = {{0.f}};
    for (int k0 = 0; k0 < K; k0 += 16) {
#pragma unroll
        for (int i = 0; i < 4; ++i) {
            int e = tid + i * 256;
            if (TA) {
                int kk = e >> 6, m = e & 63;
                As[kk][m] = A[(k0 + kk) * M + m0 + m];
            } else {
                int m = e >> 4, kk = e & 15;
                As[kk][m] = A[(m0 + m) * K + k0 + kk];
            }
            int kk2 = e >> 6, n = e & 63;
            Bs[kk2][n] = B[(k0 + kk2) * N + n0 + n];
        }
        __syncthreads();
#pragma unroll
        for (int kk = 0; kk < 16; ++kk) {
            float a[4], b[4];
#pragma unroll
            for (int i = 0; i < 4; ++i) a[i] = As[kk][ty * 4 + i];
#pragma unroll
            for (int j = 0; j < 4; ++j) b[j] = Bs[kk][tx * 4 + j];
#pragma unroll
            for (int i = 0; i < 4; ++i)
#pragma unroll
                for (int j = 0; j < 4; ++j) acc[i][j] += a[i] * b[j];
        }
        __syncthreads();
    }
#pragma unroll
    for (int i = 0; i < 4; ++i) {
        int m = m0 + ty * 4 + i;
#pragma unroll
        for (int j = 0; j < 4; ++j) {
            int n = n0 + tx * 4 + j;
            float v = acc[i][j] + bias[n];
            if (RELU) v = fmaxf(v, 0.f);
            C[m * N + n] = v;
        }
    }
}

// ---------------------------------------------------------------------------
// Copy k,v slices of qkv buffer (TOTAL x 3D) into the layer's cache rows.
// One thread per float4; grid = TOTAL*D/4/256 * ... (512 blocks x 256)
// ---------------------------------------------------------------------------
__global__ void copy_kv(const float* __restrict__ qkv, float* __restrict__ kc,
                        float* __restrict__ vc) {
    int idx = blockIdx.x * 256 + threadIdx.x;      // float4 index, TOTAL*128 total
    int row = idx >> 7, c4 = idx & 127;
    const float4* kp = (const float4*)(qkv + row * (3 * D) + D);
    const float4* vp = (const float4*)(qkv + row * (3 * D) + 2 * D);
    ((float4*)(kc + row * D))[c4] = kp[c4];
    ((float4*)(vc + row * D))[c4] = vp[c4];
}

// ---------------------------------------------------------------------------
// Zero the decode-pad rows (rows TOTAL..CACHE_ROWS) of both caches, all layers.
// ---------------------------------------------------------------------------
__global__ void zero_pads(float* __restrict__ kc, float* __restrict__ vc) {
    const int per_layer = MAX_DECODE * D / 4;  // 192000 float4
    int idx = blockIdx.x * 256 + threadIdx.x;
    int l = idx / per_layer, r = idx % per_layer;
    if (l >= LAYERS) return;
    float4 z = {0.f, 0.f, 0.f, 0.f};
    float* kbase = kc + (size_t)l * CACHE_ROWS * D + (size_t)TOTAL * D;
    float* vbase = vc + (size_t)l * CACHE_ROWS * D + (size_t)TOTAL * D;
    ((float4*)kbase)[r] = z;
    ((float4*)vbase)[r] = z;
}

// ---------------------------------------------------------------------------
// Attention for one (q, head): masked softmax over 1024 keys, then @V.
// Fully-masked rows (q >= tot) become uniform attention (matches jax softmax
// over all -1e9).
// ---------------------------------------------------------------------------
__global__ __launch_bounds__(256) void attn_kernel(const float* __restrict__ qkv,
                                                   const int* __restrict__ rl,
                                                   const int* __restrict__ tl,
                                                   const int* __restrict__ pl,
                                                   float* __restrict__ out) {
    const int q = blockIdx.x;
    const int head = blockIdx.y;
    const int tid = threadIdx.x;
    __shared__ float s[TOTAL];
    __shared__ float qv[HD];
    __shared__ float red[8];
    __shared__ float red2[8][HD + 1];
    const int xl = rl[0] + tl[0];
    const int tot = xl + pl[0];
    if (tid < HD) qv[tid] = qkv[q * (3 * D) + head * HD + tid];
    __syncthreads();
    const float scale = 0.17677669529663687f;  // 1/sqrt(32)
    float lmax = -3.4e38f;
    for (int k = tid; k < TOTAL; k += 256) {
        const float* krow = qkv + k * (3 * D) + D + head * HD;
        float d = 0.f;
#pragma unroll
        for (int j = 0; j < HD; ++j) d += qv[j] * krow[j];
        d *= scale;
        bool vq = q < tot, vk = k < tot;
        bool inv = (!vq) || (!vk) ||
                   ((q < xl) && (k >= xl) && vk) ||
                   ((q >= xl) && vq && (k >= xl) && vk && (k > q));
        d = inv ? -1e9f : d;
        s[k] = d;
        lmax = fmaxf(lmax, d);
    }
    for (int o = 32; o > 0; o >>= 1) lmax = fmaxf(lmax, __shfl_down(lmax, o));
    if ((tid & 63) == 0) red[tid >> 6] = lmax;
    __syncthreads();
    const float mx = fmaxf(fmaxf(red[0], red[1]), fmaxf(red[2], red[3]));
    float lsum = 0.f;
    for (int k = tid; k < TOTAL; k += 256) {
        float e = expf(s[k] - mx);
        s[k] = e;
        lsum += e;
    }
    for (int o = 32; o > 0; o >>= 1) lsum += __shfl_down(lsum, o);
    if ((tid & 63) == 0) red[4 + (tid >> 6)] = lsum;
    __syncthreads();
    const float inv = 1.f / (red[4] + red[5] + red[6] + red[7]);
    const int d = tid & 31, part = tid >> 5;
    float acc = 0.f;
    for (int k = part; k < TOTAL; k += 8)
        acc += s[k] * qkv[k * (3 * D) + 2 * D + head * HD + d];
    red2[part][d] = acc;
    __syncthreads();
    if (tid < HD) {
        float o2 = 0.f;
#pragma unroll
        for (int p = 0; p < 8; ++p) o2 += red2[p][tid];
        out[q * D + head * HD + tid] = o2 * inv;
    }
}

// ---------------------------------------------------------------------------
// h = LayerNorm(res + proj) * w + b    (proj already includes GEMM bias)
// One block (256 threads) per row of 512. In-place safe (hout may == res).
// ---------------------------------------------------------------------------
__global__ __launch_bounds__(256) void add_ln(const float* __restrict__ res,
                                              const float* __restrict__ proj,
                                              const float* __restrict__ lw,
                                              const float* __restrict__ lb,
                                              float* __restrict__ hout) {
    const int row = blockIdx.x, tid = threadIdx.x;
    __shared__ float red[8];
    const float x0 = res[row * D + tid] + proj[row * D + tid];
    const float x1 = res[row * D + tid + 256] + proj[row * D + tid + 256];
    float s = x0 + x1, s2 = x0 * x0 + x1 * x1;
    for (int o = 32; o > 0; o >>= 1) {
        s += __shfl_down(s, o);
        s2 += __shfl_down(s2, o);
    }
    if ((tid & 63) == 0) {
        red[tid >> 6] = s;
        red[4 + (tid >> 6)] = s2;
    }
    __syncthreads();
    const float m = (red[0] + red[1] + red[2] + red[3]) * (1.f / 512.f);
    const float var = (red[4] + red[5] + red[6] + red[7]) * (1.f / 512.f) - m * m;
    const float r = rsqrtf(var + 1e-5f);
    hout[row * D + tid] = (x0 - m) * r * lw[tid] + lb[tid];
    hout[row * D + tid + 256] = (x1 - m) * r * lw[tid + 256] + lb[tid + 256];
}

// ---------------------------------------------------------------------------
// logits[n] = h[tot-1] . predict_w[:,n] + predict_b[n]
// ---------------------------------------------------------------------------
__global__ void logits_kernel(const float* __restrict__ h, const float* __restrict__ pw,
                              const float* __restrict__ pb, const int* __restrict__ rl,
                              const int* __restrict__ tl, const int* __restrict__ pl,
                              float* __restrict__ out) {
    const int n = blockIdx.x * 256 + threadIdx.x;
    if (n >= VOCAB_AUD) return;
    int tot = rl[0] + tl[0] + pl[0];
    int last = tot - 1;
    if (last < 0) last = 0;
    const float* hr = h + last * D;
    float acc = 0.f;
    for (int d = 0; d < D; ++d) acc += hr[d] * pw[d * VOCAB_AUD + n];
    out[n] = acc + pb[n];
}

// ---------------------------------------------------------------------------
// argmax (first-index tiebreak) + scalar outputs, written as floats.
// Single block of 1024 threads.
// ---------------------------------------------------------------------------
__global__ void finalize_kernel(const float* __restrict__ logits, const int* __restrict__ rl,
                                const int* __restrict__ tl, const int* __restrict__ pl,
                                float* __restrict__ out) {
    __shared__ float vals[1024];
    __shared__ int idxs[1024];
    const int tid = threadIdx.x;
    float v = logits[tid];
    int bi = tid;
    if (tid == 0 && logits[1024] > v) { v = logits[1024]; bi = 1024; }
    vals[tid] = v;
    idxs[tid] = bi;
    __syncthreads();
    for (int s2 = 512; s2 > 0; s2 >>= 1) {
        if (tid < s2) {
            float ov = vals[tid + s2];
            int oi = idxs[tid + s2];
            if (ov > vals[tid] || (ov == vals[tid] && oi < idxs[tid])) {
                vals[tid] = ov;
                idxs[tid] = oi;
            }
        }
        __syncthreads();
    }
    if (tid == 0) {
        out[1025] = (float)idxs[0];
        out[1026] = (idxs[0] == 1024) ? 1.f : 0.f;
        out[1027] = (float)(rl[0] + tl[0] + pl[0]);
        out[1028] = (float)pl[0];
    }
}

// ---------------------------------------------------------------------------
extern "C" void kernel_launch(void* const* d_in, const int* in_sizes, int n_in,
                              void* d_out, int out_size, void* d_ws, size_t ws_size,
                              hipStream_t stream) {
    const int* prompts = (const int*)d_in[0];
    const int* p_len = (const int*)d_in[1];
    const int* ref_seq = (const int*)d_in[2];
    const int* r_len = (const int*)d_in[3];
    const int* text_seq = (const int*)d_in[4];
    const int* t_len = (const int*)d_in[5];
    const float* ref_bert = (const float*)d_in[6];
    const float* text_bert = (const float*)d_in[7];
    const float* text_emb = (const float*)d_in[8];
    const float* audio_emb = (const float*)d_in[9];
    const float* bert_w = (const float*)d_in[10];
    const float* bert_b = (const float*)d_in[11];
    const float* alpha_text = (const float*)d_in[12];
    const float* alpha_audio = (const float*)d_in[13];
    const float* qkv_w = (const float*)d_in[14];
    const float* qkv_b = (const float*)d_in[15];
    const float* out_w = (const float*)d_in[16];
    const float* out_b = (const float*)d_in[17];
    const float* ln1_w = (const float*)d_in[18];
    const float* ln1_b = (const float*)d_in[19];
    const float* ff1_w = (const float*)d_in[20];
    const float* ff1_b = (const float*)d_in[21];
    const float* ff2_w = (const float*)d_in[22];
    const float* ff2_b = (const float*)d_in[23];
    const float* ln2_w = (const float*)d_in[24];
    const float* ln2_b = (const float*)d_in[25];
    const float* pred_w = (const float*)d_in[26];
    const float* pred_b = (const float*)d_in[27];

    float* ws = (float*)d_ws;
    float* h      = ws;                // 1024*512   = 524288
    float* qkvb   = ws + 524288;       // 1024*1536  = 1572864
    float* attn_o = ws + 2097152;      // 1024*512   = 524288
    float* proj   = ws + 2621440;      // 1024*512   = 524288
    float* ffb    = ws + 3145728;      // 1024*2048  = 2097152
    float* refp   = ws + 5242880;      // 256*512    = 131072
    float* textp  = ws + 5373952;      // 256*512    = 131072
    // total 5505024 floats = 21 MB

    float* out = (float*)d_out;
    float* kc = out + 1029;                               // L*2524*512 = 31014912
    float* vc = out + 1029 + (size_t)LAYERS * CACHE_ROWS * D;

    // Zero decode-pad rows of both caches (d_out is poisoned).
    {
        int total4 = LAYERS * (MAX_DECODE * D / 4);
        zero_pads<<<(total4 + 255) / 256, 256, 0, stream>>>(kc, vc);
    }

    // BERT projections: (256 x 1024)^T-layout GEMMs. A stored K x M.
    gemm64<true, false><<<dim3(D / 64, 256 / 64), 256, 0, stream>>>(
        ref_bert, bert_w, bert_b, refp, 256, 1024, D);
    gemm64<true, false><<<dim3(D / 64, 256 / 64), 256, 0, stream>>>(
        text_bert, bert_w, bert_b, textp, 256, 1024, D);

    build_h<<<TOTAL, 256, 0, stream>>>(prompts, p_len, ref_seq, r_len, text_seq, t_len,
                                       text_emb, audio_emb, refp, textp,
                                       alpha_text, alpha_audio, h);

    for (int l = 0; l < LAYERS; ++l) {
        // qkv = h @ qkv_w[l] + qkv_b[l]
        gemm64<false, false><<<dim3(3 * D / 64, TOTAL / 64), 256, 0, stream>>>(
            h, qkv_w + (size_t)l * D * 3 * D, qkv_b + (size_t)l * 3 * D, qkvb,
            TOTAL, D, 3 * D);
        // stash k,v into caches
        copy_kv<<<TOTAL * (D / 4) / 256, 256, 0, stream>>>(
            qkvb, kc + (size_t)l * CACHE_ROWS * D, vc + (size_t)l * CACHE_ROWS * D);
        // attention
        attn_kernel<<<dim3(TOTAL, H), 256, 0, stream>>>(qkvb, r_len, t_len, p_len, attn_o);
        // out projection
        gemm64<false, false><<<dim3(D / 64, TOTAL / 64), 256, 0, stream>>>(
            attn_o, out_w + (size_t)l * D * D, out_b + (size_t)l * D, proj, TOTAL, D, D);
        // h = LN(h + proj)
        add_ln<<<TOTAL, 256, 0, stream>>>(h, proj, ln1_w + l * D, ln1_b + l * D, h);
        // ff1 (+relu)
        gemm64<false, true><<<dim3(FF / 64, TOTAL / 64), 256, 0, stream>>>(
            h, ff1_w + (size_t)l * D * FF, ff1_b + (size_t)l * FF, ffb, TOTAL, D, FF);
        // ff2
        gemm64<false, false><<<dim3(D / 64, TOTAL / 64), 256, 0, stream>>>(
            ffb, ff2_w + (size_t)l * FF * D, ff2_b + (size_t)l * D, proj, TOTAL, FF, D);
        // h = LN(h + ff2)
        add_ln<<<TOTAL, 256, 0, stream>>>(h, proj, ln2_w + l * D, ln2_b + l * D, h);
    }

    logits_kernel<<<(VOCAB_AUD + 255) / 256, 256, 0, stream>>>(
        h, pred_w, pred_b, r_len, t_len, p_len, out);
    finalize_kernel<<<1, 1024, 0, stream>>>(out, r_len, t_len, p_len, out);
}

// Round 2
// 16580.522 us; speedup vs baseline: 1.0971x; 1.0971x over previous
//
#include <hip/hip_runtime.h>

#define D 512
#define H 16
#define HD 32
#define LAYERS 24
#define FF 2048
#define MAX_DECODE 1500
#define TOTAL 1024
#define CACHE_ROWS (TOTAL + MAX_DECODE)   // 2524
#define VOCAB_AUD 1025

typedef unsigned short u16;
typedef __attribute__((ext_vector_type(8))) __bf16 bf16x8;
typedef __attribute__((ext_vector_type(4))) float f32x4;
typedef __attribute__((ext_vector_type(8))) u16 u16x8;
typedef __attribute__((ext_vector_type(4))) u16 u16x4;

__device__ __forceinline__ u16 f2bf(float f) {
    unsigned u = __builtin_bit_cast(unsigned, f);
    u += 0x7fff + ((u >> 16) & 1);   // RNE
    return (u16)(u >> 16);
}

// ---------------------------------------------------------------------------
// Sinusoidal PE
// ---------------------------------------------------------------------------
__device__ __forceinline__ float pe_val(int pos, int c) {
    int j = c & ~1;
    float div = __expf((float)j * -0.017988946039015984f);  // -log(10000)/512
    float ang = (float)pos * div;
    return (c & 1) ? __cosf(ang) : __sinf(ang);
}

// ---------------------------------------------------------------------------
// Transpose + fp32->bf16 convert:  W[K][N] (layer z) -> WT[N][K] bf16
// grid (N/32, K/32, L), block 256
// ---------------------------------------------------------------------------
__global__ __launch_bounds__(256) void transpose_cvt(const float* __restrict__ W,
                                                     u16* __restrict__ WT,
                                                     int K, int N) {
    const size_t lsz = (size_t)K * N;
    const float* Wl = W + blockIdx.z * lsz;
    u16* WTl = WT + blockIdx.z * lsz;
    __shared__ float T[32][33];
    const int t = threadIdx.x;
    const int k0 = blockIdx.y * 32, n0 = blockIdx.x * 32;
    {
        int r = t >> 5, c = t & 31;
#pragma unroll
        for (int i = 0; i < 4; ++i)
            T[r + 8 * i][c] = Wl[(size_t)(k0 + r + 8 * i) * N + n0 + c];
    }
    __syncthreads();
    {
        int n = t >> 3, cg = t & 7;
        u16x4 o;
#pragma unroll
        for (int j = 0; j < 4; ++j) o[j] = f2bf(T[cg * 4 + j][n]);
        *(u16x4*)&WTl[(size_t)(n0 + n) * K + k0 + cg * 4] = o;
    }
}

// ---------------------------------------------------------------------------
// bf16 MFMA GEMM: C[M,N] = A[M,K] @ BT[N,K]^T + bias.
// 128x128 tile, BK=32, 256 thr (4 waves 2x2, each 64x64 = 16 MFMA frags).
// M%128==0, N%128==0, K%32==0.
// ---------------------------------------------------------------------------
#define AP 40  // LDS pitch (u16): 80B rows, 16B-aligned, conflict-free frags

template <bool RELU, bool WF32, bool WBF16>
__global__ __launch_bounds__(256) void gemm_mfma(const u16* __restrict__ A,
                                                 const u16* __restrict__ BT,
                                                 const float* __restrict__ bias,
                                                 float* __restrict__ C,
                                                 u16* __restrict__ Cb,
                                                 int M, int K, int N) {
    __shared__ u16 As[128 * AP];
    __shared__ u16 Bs[128 * AP];
    const int tid = threadIdx.x;
    const int lane = tid & 63;
    const int wave = tid >> 6;
    const int wm = wave & 1, wn = wave >> 1;
    const int m0 = blockIdx.y * 128, n0 = blockIdx.x * 128;
    const int cr = lane & 15, qd = lane >> 4;
    f32x4 acc[4][4];
#pragma unroll
    for (int i = 0; i < 4; ++i)
#pragma unroll
        for (int j = 0; j < 4; ++j) acc[i][j] = (f32x4){0.f, 0.f, 0.f, 0.f};
    for (int k0 = 0; k0 < K; k0 += 32) {
#pragma unroll
        for (int i = 0; i < 2; ++i) {
            int slot = tid + i * 256;
            int r = slot >> 2, c = slot & 3;
            *(u16x8*)&As[r * AP + c * 8] =
                *(const u16x8*)&A[(size_t)(m0 + r) * K + k0 + c * 8];
            *(u16x8*)&Bs[r * AP + c * 8] =
                *(const u16x8*)&BT[(size_t)(n0 + r) * K + k0 + c * 8];
        }
        __syncthreads();
        bf16x8 af[4], bfr[4];
#pragma unroll
        for (int mi = 0; mi < 4; ++mi)
            af[mi] = *(const bf16x8*)&As[(wm * 64 + mi * 16 + cr) * AP + qd * 8];
#pragma unroll
        for (int ni = 0; ni < 4; ++ni)
            bfr[ni] = *(const bf16x8*)&Bs[(wn * 64 + ni * 16 + cr) * AP + qd * 8];
#pragma unroll
        for (int mi = 0; mi < 4; ++mi)
#pragma unroll
            for (int ni = 0; ni < 4; ++ni)
                acc[mi][ni] = __builtin_amdgcn_mfma_f32_16x16x32_bf16(
                    af[mi], bfr[ni], acc[mi][ni], 0, 0, 0);
        __syncthreads();
    }
#pragma unroll
    for (int mi = 0; mi < 4; ++mi)
#pragma unroll
        for (int ni = 0; ni < 4; ++ni) {
            int n = n0 + wn * 64 + ni * 16 + cr;
            float bn = bias[n];
#pragma unroll
            for (int r = 0; r < 4; ++r) {
                int mm = m0 + wm * 64 + mi * 16 + qd * 4 + r;
                float v = acc[mi][ni][r] + bn;
                if (RELU) v = fmaxf(v, 0.f);
                if (WF32) C[(size_t)mm * N + n] = v;
                if (WBF16) Cb[(size_t)mm * N + n] = f2bf(v);
            }
        }
}

// ---------------------------------------------------------------------------
// Build packed input h (fp32 + bf16)
// ---------------------------------------------------------------------------
__global__ void build_h(const int* __restrict__ prompts, const int* __restrict__ pl,
                        const int* __restrict__ ref_seq, const int* __restrict__ rl,
                        const int* __restrict__ text_seq, const int* __restrict__ tl,
                        const float* __restrict__ text_emb, const float* __restrict__ audio_emb,
                        const float* __restrict__ refproj, const float* __restrict__ textproj,
                        const float* __restrict__ alpha_text, const float* __restrict__ alpha_audio,
                        float* __restrict__ h, u16* __restrict__ hb) {
    const int t = blockIdx.x;
    const int ref_len = rl[0], text_len = tl[0], p_len = pl[0];
    const int x_len = ref_len + text_len;
    const int tot = x_len + p_len;
    const float at = alpha_text[0], aa = alpha_audio[0];
    for (int c = threadIdx.x; c < D; c += 256) {
        float val = 0.f;
        if (t < x_len) {
            float pe = at * pe_val(t, c);
            if (t < ref_len)
                val = text_emb[ref_seq[t] * D + c] + refproj[t * D + c] + pe;
            else
                val = text_emb[text_seq[t - ref_len] * D + c] + textproj[(t - ref_len) * D + c] + pe;
        } else if (t < tot) {
            int i = t - x_len;
            float pe = aa * pe_val(i, c);
            float a = (i < p_len) ? audio_emb[prompts[i] * D + c] : 0.f;
            val = a + pe;
        }
        h[t * D + c] = val;
        hb[t * D + c] = f2bf(val);
    }
}

// ---------------------------------------------------------------------------
// Copy k,v slices of qkv buffer into the layer's cache rows.
// ---------------------------------------------------------------------------
__global__ void copy_kv(const float* __restrict__ qkv, float* __restrict__ kc,
                        float* __restrict__ vc) {
    int idx = blockIdx.x * 256 + threadIdx.x;
    int row = idx >> 7, c4 = idx & 127;
    const float4* kp = (const float4*)(qkv + row * (3 * D) + D);
    const float4* vp = (const float4*)(qkv + row * (3 * D) + 2 * D);
    ((float4*)(kc + row * D))[c4] = kp[c4];
    ((float4*)(vc + row * D))[c4] = vp[c4];
}

__global__ void zero_pads(float* __restrict__ kc, float* __restrict__ vc) {
    const int per_layer = MAX_DECODE * D / 4;
    int idx = blockIdx.x * 256 + threadIdx.x;
    int l = idx / per_layer, r = idx % per_layer;
    if (l >= LAYERS) return;
    float4 z = {0.f, 0.f, 0.f, 0.f};
    float* kbase = kc + (size_t)l * CACHE_ROWS * D + (size_t)TOTAL * D;
    float* vbase = vc + (size_t)l * CACHE_ROWS * D + (size_t)TOTAL * D;
    ((float4*)kbase)[r] = z;
    ((float4*)vbase)[r] = z;
}

// ---------------------------------------------------------------------------
// Attention: block = (head, 64-q tile). K/V tiles in LDS, wave-broadcast
// reads, per-thread 32-key register score tile, online softmax, 4-way
// partition combine in LDS. Output bf16 (feeds out-proj GEMM).
// ---------------------------------------------------------------------------
__global__ __launch_bounds__(256) void attn2(const float* __restrict__ qkv,
                                             const int* __restrict__ rl,
                                             const int* __restrict__ tl,
                                             const int* __restrict__ pl,
                                             u16* __restrict__ outb) {
    __shared__ float smem[2 * 128 * 36];  // Ks | Vs, aliased for combine
    const int head = blockIdx.x;
    const int q0 = blockIdx.y * 64;
    const int t = threadIdx.x;
    const int qq = t & 63, p = t >> 6;
    const int qi = q0 + qq;
    const int xl = rl[0] + tl[0];
    const int tot = xl + pl[0];
    const bool vq = qi < tot;
    const float scale = 0.17677669529663687f;  // 1/sqrt(32)
    const float* qp = qkv + (size_t)qi * 1536 + head * 32;
    f32x4 qv[8];
#pragma unroll
    for (int c = 0; c < 8; ++c) qv[c] = *(const f32x4*)(qp + c * 4);
    f32x4 o[8];
#pragma unroll
    for (int c = 0; c < 8; ++c) o[c] = (f32x4){0.f, 0.f, 0.f, 0.f};
    float m = -3.0e38f, l = 0.f;
    for (int kt = 0; kt < 8; ++kt) {
        {
            int row = t >> 1, half = t & 1;
            const float* kp = qkv + (size_t)(kt * 128 + row) * 1536 + 512 + head * 32 + half * 16;
            const float* vp = kp + 512;
#pragma unroll
            for (int i = 0; i < 4; ++i) {
                *(f32x4*)&smem[row * 36 + half * 16 + i * 4] = *(const f32x4*)(kp + i * 4);
                *(f32x4*)&smem[128 * 36 + row * 36 + half * 16 + i * 4] = *(const f32x4*)(vp + i * 4);
            }
        }
        __syncthreads();
        float sc[32];
        float tmax = -3.0e38f;
#pragma unroll
        for (int kk = 0; kk < 32; ++kk) {
            const float* kr = &smem[(p * 32 + kk) * 36];
            f32x4 a = (f32x4){0.f, 0.f, 0.f, 0.f};
#pragma unroll
            for (int c = 0; c < 8; ++c) a += qv[c] * *(const f32x4*)(kr + c * 4);
            float s = (a.x + a.y + a.z + a.w) * scale;
            int kg = kt * 128 + p * 32 + kk;
            bool vk = kg < tot;
            bool inv = (!vq) || (!vk) ||
                       ((qi < xl) ? (kg >= xl) : ((kg >= xl) && (kg > qi)));
            s = inv ? -1.0e9f : s;
            sc[kk] = s;
            tmax = fmaxf(tmax, s);
        }
        float mn = fmaxf(m, tmax);
        float f = __expf(m - mn);
        l *= f;
#pragma unroll
        for (int c = 0; c < 8; ++c) o[c] *= f;
#pragma unroll
        for (int kk = 0; kk < 32; ++kk) {
            float pw = __expf(sc[kk] - mn);
            l += pw;
            const float* vr = &smem[128 * 36 + (p * 32 + kk) * 36];
#pragma unroll
            for (int c = 0; c < 8; ++c) o[c] += pw * *(const f32x4*)(vr + c * 4);
        }
        m = mn;
        __syncthreads();
    }
    {   // write partials: layout per (p,q): [m, l, _, _, o0..o31], stride 36
        int base = (p * 64 + qq) * 36;
        smem[base] = m;
        smem[base + 1] = l;
#pragma unroll
        for (int c = 0; c < 8; ++c) *(f32x4*)&smem[base + 4 + c * 4] = o[c];
    }
    __syncthreads();
    {
        int dc = t >> 6;
        float mp[4], lp[4];
        float M2 = -3.0e38f;
#pragma unroll
        for (int pp = 0; pp < 4; ++pp) {
            mp[pp] = smem[(pp * 64 + qq) * 36];
            lp[pp] = smem[(pp * 64 + qq) * 36 + 1];
            M2 = fmaxf(M2, mp[pp]);
        }
        float L = 0.f, w[4];
#pragma unroll
        for (int pp = 0; pp < 4; ++pp) {
            w[pp] = __expf(mp[pp] - M2);
            L += lp[pp] * w[pp];
        }
        float invL = 1.f / L;
#pragma unroll
        for (int j = 0; j < 8; ++j) {
            int d = dc * 8 + j;
            float val = 0.f;
#pragma unroll
            for (int pp = 0; pp < 4; ++pp)
                val += smem[(pp * 64 + qq) * 36 + 4 + d] * w[pp];
            outb[(size_t)qi * D + head * HD + d] = f2bf(val * invL);
        }
    }
}

// ---------------------------------------------------------------------------
// h = LayerNorm(res + proj) * w + b  -> fp32 h AND bf16 hb
// ---------------------------------------------------------------------------
__global__ __launch_bounds__(256) void add_ln(const float* __restrict__ res,
                                              const float* __restrict__ proj,
                                              const float* __restrict__ lw,
                                              const float* __restrict__ lb,
                                              float* __restrict__ hout,
                                              u16* __restrict__ hbout) {
    const int row = blockIdx.x, tid = threadIdx.x;
    __shared__ float red[8];
    const float x0 = res[row * D + tid] + proj[row * D + tid];
    const float x1 = res[row * D + tid + 256] + proj[row * D + tid + 256];
    float s = x0 + x1, s2 = x0 * x0 + x1 * x1;
    for (int o = 32; o > 0; o >>= 1) {
        s += __shfl_down(s, o);
        s2 += __shfl_down(s2, o);
    }
    if ((tid & 63) == 0) {
        red[tid >> 6] = s;
        red[4 + (tid >> 6)] = s2;
    }
    __syncthreads();
    const float mean = (red[0] + red[1] + red[2] + red[3]) * (1.f / 512.f);
    const float var = (red[4] + red[5] + red[6] + red[7]) * (1.f / 512.f) - mean * mean;
    const float r = rsqrtf(var + 1e-5f);
    float y0 = (x0 - mean) * r * lw[tid] + lb[tid];
    float y1 = (x1 - mean) * r * lw[tid + 256] + lb[tid + 256];
    hout[row * D + tid] = y0;
    hout[row * D + tid + 256] = y1;
    hbout[row * D + tid] = f2bf(y0);
    hbout[row * D + tid + 256] = f2bf(y1);
}

// ---------------------------------------------------------------------------
__global__ void logits_kernel(const float* __restrict__ h, const float* __restrict__ pw,
                              const float* __restrict__ pb, const int* __restrict__ rl,
                              const int* __restrict__ tl, const int* __restrict__ pl,
                              float* __restrict__ out) {
    const int n = blockIdx.x * 256 + threadIdx.x;
    if (n >= VOCAB_AUD) return;
    int tot = rl[0] + tl[0] + pl[0];
    int last = tot - 1;
    if (last < 0) last = 0;
    const float* hr = h + last * D;
    float acc = 0.f;
    for (int d = 0; d < D; ++d) acc += hr[d] * pw[d * VOCAB_AUD + n];
    out[n] = acc + pb[n];
}

__global__ void finalize_kernel(const float* __restrict__ logits, const int* __restrict__ rl,
                                const int* __restrict__ tl, const int* __restrict__ pl,
                                float* __restrict__ out) {
    __shared__ float vals[1024];
    __shared__ int idxs[1024];
    const int tid = threadIdx.x;
    float v = logits[tid];
    int bi = tid;
    if (tid == 0 && logits[1024] > v) { v = logits[1024]; bi = 1024; }
    vals[tid] = v;
    idxs[tid] = bi;
    __syncthreads();
    for (int s2 = 512; s2 > 0; s2 >>= 1) {
        if (tid < s2) {
            float ov = vals[tid + s2];
            int oi = idxs[tid + s2];
            if (ov > vals[tid] || (ov == vals[tid] && oi < idxs[tid])) {
                vals[tid] = ov;
                idxs[tid] = oi;
            }
        }
        __syncthreads();
    }
    if (tid == 0) {
        out[1025] = (float)idxs[0];
        out[1026] = (idxs[0] == 1024) ? 1.f : 0.f;
        out[1027] = (float)(rl[0] + tl[0] + pl[0]);
        out[1028] = (float)pl[0];
    }
}

// ---------------------------------------------------------------------------
extern "C" void kernel_launch(void* const* d_in, const int* in_sizes, int n_in,
                              void* d_out, int out_size, void* d_ws, size_t ws_size,
                              hipStream_t stream) {
    const int* prompts = (const int*)d_in[0];
    const int* p_len = (const int*)d_in[1];
    const int* ref_seq = (const int*)d_in[2];
    const int* r_len = (const int*)d_in[3];
    const int* text_seq = (const int*)d_in[4];
    const int* t_len = (const int*)d_in[5];
    const float* ref_bert = (const float*)d_in[6];
    const float* text_bert = (const float*)d_in[7];
    const float* text_emb = (const float*)d_in[8];
    const float* audio_emb = (const float*)d_in[9];
    const float* bert_w = (const float*)d_in[10];
    const float* bert_b = (const float*)d_in[11];
    const float* alpha_text = (const float*)d_in[12];
    const float* alpha_audio = (const float*)d_in[13];
    const float* qkv_w = (const float*)d_in[14];
    const float* qkv_b = (const float*)d_in[15];
    const float* out_w = (const float*)d_in[16];
    const float* out_b = (const float*)d_in[17];
    const float* ln1_w = (const float*)d_in[18];
    const float* ln1_b = (const float*)d_in[19];
    const float* ff1_w = (const float*)d_in[20];
    const float* ff1_b = (const float*)d_in[21];
    const float* ff2_w = (const float*)d_in[22];
    const float* ff2_b = (const float*)d_in[23];
    const float* ln2_w = (const float*)d_in[24];
    const float* ln2_b = (const float*)d_in[25];
    const float* pred_w = (const float*)d_in[26];
    const float* pred_b = (const float*)d_in[27];

    // ---- workspace carve-up ----
    float* ws = (float*)d_ws;
    float* h = ws;                       // 524288 f
    float* proj = h + 524288;            // 524288 f
    float* qkvb = proj + 524288;         // 1572864 f
    float* refp = qkvb + 1572864;        // 131072 f
    float* textp = refp + 131072;        // 131072 f
    u16* hb = (u16*)(textp + 131072);    // 524288 u
    u16* attn_ob = hb + 524288;          // 524288 u
    u16* ffb = attn_ob + 524288;         // 2097152 u
    u16* refT = ffb + 2097152;           // 262144 u
    u16* textT = refT + 262144;          // 262144 u
    u16* bertwT = textT + 262144;        // 524288 u
    u16* wbase = bertwT + 524288;

    const size_t W_QKV = (size_t)D * 3 * D;      // 786432
    const size_t W_OUT = (size_t)D * D;          // 262144
    const size_t W_FF1 = (size_t)D * FF;         // 1048576
    const size_t W_FF2 = (size_t)FF * D;         // 1048576
    const size_t W_ALL = W_QKV + W_OUT + W_FF1 + W_FF2;  // 3145728 per layer

    const size_t need_full = ((char*)(wbase + LAYERS * W_ALL) - (char*)ws);
    const bool full = ws_size >= need_full;

    u16* qkvT = wbase;
    u16* outT = qkvT + (full ? LAYERS * W_QKV : 0);
    u16* ff1T = outT + (full ? LAYERS * W_OUT : 0);
    u16* ff2T = ff1T + (full ? LAYERS * W_FF1 : 0);
    if (!full) {  // per-layer scratch slots
        qkvT = wbase;
        outT = qkvT + W_QKV;
        ff1T = outT + W_OUT;
        ff2T = ff1T + W_FF1;
    }

    float* out = (float*)d_out;
    float* kc = out + 1029;
    float* vc = out + 1029 + (size_t)LAYERS * CACHE_ROWS * D;

    // zero decode-pad rows of caches
    {
        int total4 = LAYERS * (MAX_DECODE * D / 4);
        zero_pads<<<(total4 + 255) / 256, 256, 0, stream>>>(kc, vc);
    }

    // transpose+convert: bert inputs and bert weight
    transpose_cvt<<<dim3(256 / 32, 1024 / 32, 1), 256, 0, stream>>>(ref_bert, refT, 1024, 256);
    transpose_cvt<<<dim3(256 / 32, 1024 / 32, 1), 256, 0, stream>>>(text_bert, textT, 1024, 256);
    transpose_cvt<<<dim3(D / 32, 1024 / 32, 1), 256, 0, stream>>>(bert_w, bertwT, 1024, D);
    if (full) {
        transpose_cvt<<<dim3(3 * D / 32, D / 32, LAYERS), 256, 0, stream>>>(qkv_w, qkvT, D, 3 * D);
        transpose_cvt<<<dim3(D / 32, D / 32, LAYERS), 256, 0, stream>>>(out_w, outT, D, D);
        transpose_cvt<<<dim3(FF / 32, D / 32, LAYERS), 256, 0, stream>>>(ff1_w, ff1T, D, FF);
        transpose_cvt<<<dim3(D / 32, FF / 32, LAYERS), 256, 0, stream>>>(ff2_w, ff2T, FF, D);
    }

    // bert projections (MFMA): refp = refT(256x1024) @ bertwT^T + bert_b
    gemm_mfma<false, true, false><<<dim3(D / 128, 256 / 128), 256, 0, stream>>>(
        refT, bertwT, bert_b, refp, nullptr, 256, 1024, D);
    gemm_mfma<false, true, false><<<dim3(D / 128, 256 / 128), 256, 0, stream>>>(
        textT, bertwT, bert_b, textp, nullptr, 256, 1024, D);

    build_h<<<TOTAL, 256, 0, stream>>>(prompts, p_len, ref_seq, r_len, text_seq, t_len,
                                       text_emb, audio_emb, refp, textp,
                                       alpha_text, alpha_audio, h, hb);

    for (int l = 0; l < LAYERS; ++l) {
        u16 *wQ, *wO, *wF1, *wF2;
        if (full) {
            wQ = qkvT + l * W_QKV;
            wO = outT + l * W_OUT;
            wF1 = ff1T + l * W_FF1;
            wF2 = ff2T + l * W_FF2;
        } else {
            transpose_cvt<<<dim3(3 * D / 32, D / 32, 1), 256, 0, stream>>>(
                qkv_w + l * W_QKV, qkvT, D, 3 * D);
            transpose_cvt<<<dim3(D / 32, D / 32, 1), 256, 0, stream>>>(
                out_w + l * W_OUT, outT, D, D);
            transpose_cvt<<<dim3(FF / 32, D / 32, 1), 256, 0, stream>>>(
                ff1_w + l * W_FF1, ff1T, D, FF);
            transpose_cvt<<<dim3(D / 32, FF / 32, 1), 256, 0, stream>>>(
                ff2_w + l * W_FF2, ff2T, FF, D);
            wQ = qkvT; wO = outT; wF1 = ff1T; wF2 = ff2T;
        }
        // qkv = hb @ wQ^T + b
        gemm_mfma<false, true, false><<<dim3(3 * D / 128, TOTAL / 128), 256, 0, stream>>>(
            hb, wQ, qkv_b + (size_t)l * 3 * D, qkvb, nullptr, TOTAL, D, 3 * D);
        copy_kv<<<TOTAL * (D / 4) / 256, 256, 0, stream>>>(
            qkvb, kc + (size_t)l * CACHE_ROWS * D, vc + (size_t)l * CACHE_ROWS * D);
        attn2<<<dim3(H, TOTAL / 64), 256, 0, stream>>>(qkvb, r_len, t_len, p_len, attn_ob);
        gemm_mfma<false, true, false><<<dim3(D / 128, TOTAL / 128), 256, 0, stream>>>(
            attn_ob, wO, out_b + (size_t)l * D, proj, nullptr, TOTAL, D, D);
        add_ln<<<TOTAL, 256, 0, stream>>>(h, proj, ln1_w + l * D, ln1_b + l * D, h, hb);
        gemm_mfma<true, false, true><<<dim3(FF / 128, TOTAL / 128), 256, 0, stream>>>(
            hb, wF1, ff1_b + (size_t)l * FF, nullptr, ffb, TOTAL, D, FF);
        gemm_mfma<false, true, false><<<dim3(D / 128, TOTAL / 128), 256, 0, stream>>>(
            ffb, wF2, ff2_b + (size_t)l * D, proj, nullptr, TOTAL, FF, D);
        add_ln<<<TOTAL, 256, 0, stream>>>(h, proj, ln2_w + l * D, ln2_b + l * D, h, hb);
    }

    logits_kernel<<<(VOCAB_AUD + 255) / 256, 256, 0, stream>>>(
        h, pred_w, pred_b, r_len, t_len, p_len, out);
    finalize_kernel<<<1, 1024, 0, stream>>>(out, r_len, t_len, p_len, out);
}